// Round 15
// baseline (115.610 us; speedup 1.0000x reference)
//
#include <hip/hip_runtime.h>
#include <cstdint>
#include <cstddef>

#define NB 8
#define NS 2048
#define ND 768
#define NSP 512
#define MAXW 30
#define NH 100
#define LDPH 56        // f16 P row stride in uints (112 halves; 100 used)
#define NKS 24         // 768 / 32 k-steps
#define NCF 8          // 8 col-frags of 16 (cols 0..99 = h, 100 = logit, 101..127 = 0)
#define BM 16          // proj rows per block tile
#define NIT 12         // proj outer iters (BK = 64)

typedef __attribute__((ext_vector_type(8))) _Float16 half8;
typedef __attribute__((ext_vector_type(2))) __fp16 fp16x2;
typedef __attribute__((ext_vector_type(4))) float floatx4;

union U4H8 { uint4 v; half8 h8; unsigned u[4]; unsigned short us[8]; };
union H2U  { fp16x2 h; unsigned u; };

__device__ inline unsigned short f2h(float f) {   // RNE f32->f16
    _Float16 h = (_Float16)f;
    union { _Float16 hh; unsigned short us; } c; c.hh = h;
    return c.us;
}

// Kernel 0: pack B = [ffnn_w | att_w | 0] (768 x 128) into MFMA B-frag order, f16.
// Frag (ks, cf) at (ks*8+cf)*64: lane l holds B[ks*32 + (l>>4)*8 + j][cf*16 + (l&15)].
__global__ __launch_bounds__(256) void pack_b_kernel(
    const float* __restrict__ ffnn_w, const float* __restrict__ att_w,
    uint4* __restrict__ Bfrag)
{
    int ks = blockIdx.x;
    for (int idx = threadIdx.x; idx < NCF * 64; idx += 256) {
        int cf = idx >> 6, lane = idx & 63;
        int q = lane >> 4, r = lane & 15;
        int n = cf * 16 + r;
        U4H8 p;
#pragma unroll
        for (int j = 0; j < 8; j++) {
            int k = ks * 32 + q * 8 + j;
            float v = (n < NH) ? ffnn_w[(size_t)k * NH + n]
                               : (n == NH ? att_w[k] : 0.f);
            p.us[j] = f2h(v);
        }
        Bfrag[(size_t)(ks * NCF + cf) * 64 + lane] = p.v;
    }
}

// Kernel 1: proj in f16. 1024 blocks x 256 threads (launch_bounds 256,6 ->
// up to 24 waves/CU). Tile 16 rows x 128 cols; A f32->f16 via v_cvt_pkrtz at
// staging into LDS; two-barrier pipelined K-loop; B register-direct from L2.
// Writes P (f16, cols 0..99) and Lg (f32 logit).
__global__ __launch_bounds__(256, 6) void proj_kernel(
    const float* __restrict__ seq, const uint4* __restrict__ Bfrag,
    unsigned short* __restrict__ Ph, float* __restrict__ Lg)
{
    __shared__ unsigned Ah[BM][36];    // f16 pairs; 64 k/row = 32 uints + 4 pad
    const int t = threadIdx.x;
    const int wave = t >> 6, lane = t & 63;
    const int q = lane >> 4, r = lane & 15;
    const int cf0 = wave * 2;
    const int row0 = blockIdx.x * BM;

    floatx4 acc[2] = {{0.f,0.f,0.f,0.f},{0.f,0.f,0.f,0.f}};

    const int sr = t >> 4, sc = t & 15;
    const float4* gA = (const float4*)(seq + (size_t)(row0 + sr) * ND);
    float4 sv = gA[sc];

    const uint4* bp = Bfrag + (size_t)cf0 * 64 + lane;
    uint4 Bc0 = bp[0], Bc1 = bp[64], Bc2 = bp[512], Bc3 = bp[512 + 64];

    for (int i = 0; i < NIT; ++i) {
        H2U u01, u23;
        u01.h = __builtin_amdgcn_cvt_pkrtz(sv.x, sv.y);
        u23.h = __builtin_amdgcn_cvt_pkrtz(sv.z, sv.w);
        __syncthreads();                     // prior iter's LDS reads done
        { uint2 u; u.x = u01.u; u.y = u23.u; *(uint2*)&Ah[sr][sc * 2] = u; }
        __syncthreads();                     // tile i visible

        const int ni = (i + 1 < NIT) ? i + 1 : i;
        sv = gA[ni * 16 + sc];               // prefetch A tile i+1
        const size_t nb = (size_t)ni * 1024;
        uint4 Bn0 = bp[nb], Bn1 = bp[nb + 64], Bn2 = bp[nb + 512], Bn3 = bp[nb + 512 + 64];

#pragma unroll
        for (int ksl = 0; ksl < 2; ++ksl) {
            U4H8 a, b0, b1;
            a.v  = *(const uint4*)&Ah[r][ksl * 16 + q * 4];
            b0.v = ksl ? Bc2 : Bc0;
            b1.v = ksl ? Bc3 : Bc1;
            acc[0] = __builtin_amdgcn_mfma_f32_16x16x32_f16(a.h8, b0.h8, acc[0], 0, 0, 0);
            acc[1] = __builtin_amdgcn_mfma_f32_16x16x32_f16(a.h8, b1.h8, acc[1], 0, 0, 0);
        }
        Bc0 = Bn0; Bc1 = Bn1; Bc2 = Bn2; Bc3 = Bn3;
    }

    // C/D layout: col = (cf0+c)*16 + r, row = row0 + q*4 + reg
#pragma unroll
    for (int c = 0; c < 2; ++c) {
        const int col = (cf0 + c) * 16 + r;
        const int rowb = row0 + q * 4;
        if (col < NH) {
#pragma unroll
            for (int reg = 0; reg < 4; ++reg)
                Ph[(size_t)(rowb + reg) * (2 * LDPH) + col] = f2h(acc[c][reg]);
        } else if (col == NH) {
#pragma unroll
            for (int reg = 0; reg < 4; ++reg)
                Lg[rowb + reg] = acc[c][reg];
        }
    }
}

// Kernel 2: two spans per wave (half-wave each). Softmax over Lg (att_b
// cancels); gather f16 P rows (uint2/lane = 4 h-cols, 4 cache lines/row);
// loads predicated on i<w. XCD batch-affinity swizzle: blockIdx&7 = batch,
// so each batch's 450 KB P slice concentrates in one XCD's L2.
__global__ __launch_bounds__(256, 4) void span_kernel(
    const int* __restrict__ span_idx, const int* __restrict__ span_mask,
    const unsigned* __restrict__ Ph, const float* __restrict__ Lg,
    const float* __restrict__ ffnn_b, float* __restrict__ out)
{
    const int hw = threadIdx.x >> 5, lane = threadIdx.x & 31;
    const int b = blockIdx.x & 7, j = blockIdx.x >> 3;
    const int gs = b * NSP + j * 8 + hw;           // [0, 4096)
    const int st = span_idx[2 * gs];
    int w = span_idx[2 * gs + 1] - st;             // width in [1, MAXW]
    w = max(1, min(w, MAXW));

    float lg = (lane < w) ? Lg[b * NS + st + lane] : -1e30f;
    float mx = lg;
#pragma unroll
    for (int off = 16; off > 0; off >>= 1) mx = fmaxf(mx, __shfl_xor(mx, off, 32));
    float e = (lane < w) ? __expf(lg - mx) : 0.f;
    float sum = e;
#pragma unroll
    for (int off = 16; off > 0; off >>= 1) sum += __shfl_xor(sum, off, 32);
    float attn = e / sum;                          // 0 for lanes >= w

    const int cl = min(lane, 24);                  // lane cl owns h = 4cl..4cl+3
    const unsigned* Pb = Ph + (size_t)(b * NS + st) * LDPH + cl * 2;
    float4 acc = {0.f, 0.f, 0.f, 0.f};
#pragma unroll
    for (int i = 0; i < MAXW; ++i) {
        float a = __shfl(attn, i, 32);
        if (i < w) {                               // half-uniform predicate
            uint2 v = *(const uint2*)(Pb + i * LDPH);
            H2U p0, p1; p0.u = v.x; p1.u = v.y;
            acc.x += a * (float)p0.h.x; acc.y += a * (float)p0.h.y;
            acc.z += a * (float)p1.h.x; acc.w += a * (float)p1.h.y;
        }
    }

    if (lane < 25) {
        float m = (float)span_mask[gs];
        float4 bias = ((const float4*)ffnn_b)[lane];
        float4 o;
        o.x = tanhf(m * acc.x + bias.x);
        o.y = tanhf(m * acc.y + bias.y);
        o.z = tanhf(m * acc.z + bias.z);
        o.w = tanhf(m * acc.w + bias.w);
        *(float4*)(out + (size_t)gs * NH + 4 * lane) = o;
    }
}

extern "C" void kernel_launch(void* const* d_in, const int* in_sizes, int n_in,
                              void* d_out, int out_size, void* d_ws, size_t ws_size,
                              hipStream_t stream) {
    const float* seq      = (const float*)d_in[0];  // [B,S,D]
    const int*   span_idx = (const int*)d_in[1];    // [B,N,2] int32 on device
    const int*   span_msk = (const int*)d_in[2];    // [B,N]
    const float* att_w    = (const float*)d_in[3];  // [D,1]
    // d_in[4] = att_b: cancels inside softmax — unused
    const float* ffnn_w   = (const float*)d_in[5];  // [D,H]
    const float* ffnn_b   = (const float*)d_in[6];  // [H]
    float* out = (float*)d_out;                     // [B,N,H]

    char* ws = (char*)d_ws;
    size_t off = 0;
    unsigned* Ph = (unsigned*)(ws + off); off += (size_t)NB * NS * LDPH * 4;  // 3.67 MB
    uint4* Bfrag = (uint4*)(ws + off);    off += (size_t)NKS * NCF * 64 * 16; // 192 KB
    float* Lg    = (float*)(ws + off);                                        // 64 KB

    pack_b_kernel<<<NKS, 256, 0, stream>>>(ffnn_w, att_w, Bfrag);
    proj_kernel<<<(NB * NS) / BM, 256, 0, stream>>>(seq, Bfrag, (unsigned short*)Ph, Lg);
    span_kernel<<<(NB * NSP) / 8, 256, 0, stream>>>(span_idx, span_msk, Ph, Lg, ffnn_b, out);
}